// Round 12
// baseline (1492.597 us; speedup 1.0000x reference)
//
#include <hip/hip_runtime.h>

typedef float v2f __attribute__((ext_vector_type(2)));

#define HID 32
#define LOG2E 1.4426950408889634f

#if __has_builtin(__builtin_amdgcn_exp2f)
#define EXP2(x) __builtin_amdgcn_exp2f(x)
#else
#define EXP2(x) exp2f(x)
#endif
#if __has_builtin(__builtin_amdgcn_rcpf)
#define RCP(x) __builtin_amdgcn_rcpf(x)
#else
#define RCP(x) (1.0f / (x))
#endif

// Guaranteed packed fp32 FMA (1 inst / 2 MACs). Operands in arch VGPRs;
// safe under the (2,2) 256-reg budget (~190 live regs fit, no AGPR split).
#define PKFMA(acc, w, h) \
    asm("v_pk_fma_f32 %0, %1, %2, %0" : "+v"(acc) : "v"(w), "v"(h))

// xor-butterfly add within 32-lane groups (each group holds every hidden unit
// exactly once; halves reduce independently)
#define SWZ_ADD(p, imm) do {                                            \
    int _t = __builtin_amdgcn_ds_swizzle(__float_as_int(p), (imm));     \
    (p) += __int_as_float(_t); } while (0)
#define REDUCE32(p) do {                                                \
    SWZ_ADD(p, 0x041F); SWZ_ADD(p, 0x081F); SWZ_ADD(p, 0x101F);        \
    SWZ_ADD(p, 0x201F); SWZ_ADD(p, 0x401F); } while (0)

// waves_per_eu(2,2): pin EXACTLY 2 waves/SIMD (256-reg budget). R4 lesson:
// never leave the max open (allocator chases occupancy and spills).
__global__ __attribute__((amdgpu_waves_per_eu(2, 2))) __launch_bounds__(256)
void lstm_dual2(const float* __restrict__ poses,
                const float* W_ih_,      // deliberately NOT restrict/laundered:
                const float* W_hh_,      // weight loads must not be remat-able
                const float* W_dense_,   // inside the loops
                float* __restrict__ out,
                int B, int T_enc, int T_dec)
{
    // Launder weight pointers: breaks provenance, so re-executing a weight
    // load inside a loop containing global stores is no longer provably
    // equivalent -> the loaded VALUES must stay register-resident. This is
    // the remat-killer that R1/R2's PIN (one-time materialization) wasn't.
    const float* W_ih = W_ih_;       asm volatile("" : "+s"(W_ih));
    const float* W_hh = W_hh_;       asm volatile("" : "+s"(W_hh));
    const float* W_dense = W_dense_; asm volatile("" : "+s"(W_dense));

    // two elements per wave; hx row pair is wave-private -> NO barriers
    __shared__ __align__(16) float hx[4][2][HID];

    const int tid  = threadIdx.x;
    const int lane = tid & 63;
    const int wv   = tid >> 6;          // wave within block (0..3)
    const int k    = lane & 31;         // hidden unit
    const int isH  = lane >> 5;         // 0: rows {k,64+k}=(i,g); 1: {32+k,96+k}=(f,o)
    const int el0  = (blockIdx.x * 4 + wv) * 2;   // this wave's two elements
    const int el1  = el0 + 1;

    const int rowA = isH * 32 + k;      // i or f
    const int rowB = rowA + 64;         // g or o

    // ---- persistent weights: 72 floats/lane, shared by both elements ----
    const v2f* Wih2 = reinterpret_cast<const v2f*>(W_ih);
    v2f wA0 = Wih2[2 * rowA], wA1 = Wih2[2 * rowA + 1];
    v2f wB0 = Wih2[2 * rowB], wB1 = Wih2[2 * rowB + 1];
    v2f whhA[16], whhB[16];
    {
        const v2f* Whh2 = reinterpret_cast<const v2f*>(W_hh);
        #pragma unroll
        for (int j = 0; j < 16; ++j) {
            whhA[j] = Whh2[rowA * 16 + j];
            whhB[j] = Whh2[rowB * 16 + j];
        }
    }
    // velocity weight, half-split: half0 holds W_dense row 1, half1 row 2
    const float wsel = isH ? W_dense[2 * HID + k] : W_dense[HID + k];

    // branchless activation selectors: rowA always sigmoid; rowB tanh|sigmoid
    const float S1 = isH ? -LOG2E : 2.0f * LOG2E;
    const float A1 = isH ? 0.0f : 1.0f;
    const float B1 = isH ? 1.0f : -2.0f;

    v2f h2a[16], h2b[16];
    #pragma unroll
    for (int j = 0; j < 16; ++j) { h2a[j] = (v2f){0.f, 0.f}; h2b[j] = (v2f){0.f, 0.f}; }
    float c0 = 0.f, c1 = 0.f, hk0 = 0.f, hk1 = 0.f;
    float v10, v20, v11, v21;

    const float4* poses4 = reinterpret_cast<const float4*>(poses);
    float4*       out4   = reinterpret_cast<float4*>(out);

    float* __restrict__ hrow = &hx[wv][0][0];   // 64 floats: [elem0 32][elem1 32]

    // gate finish for one element (both halves duplicate c/h: no extra shfl)
    auto finish = [&](v2f aA, v2f aB, float& c, float& hk) {
        const float a0 = aA.x + aA.y;       // i or f pre-activation
        const float a1 = aB.x + aB.y;       // g or o pre-activation
        const float act0 = RCP(1.0f + EXP2(-LOG2E * a0));          // sigmoid
        const float act1 = fmaf(B1, RCP(1.0f + EXP2(S1 * a1)), A1);
        const float xo0 = __shfl_xor(act0, 32, 64);
        const float xo1 = __shfl_xor(act1, 32, 64);
        const float i_ = isH ? xo0  : act0;
        const float f_ = isH ? act0 : xo0;
        const float g_ = isH ? xo1  : act1;
        const float o_ = isH ? act1 : xo1;
        c = fmaf(f_, c, i_ * g_);
        const float th = fmaf(-2.0f, RCP(1.0f + EXP2((2.0f * LOG2E) * c)), 1.0f);
        hk = o_ * th;                       // identical in lanes k and k+32
    };

    // one LSTM step for BOTH elements. 8 independent 8-deep pk chains
    // (split 16 -> 8+8) so FMA latency hides even at 2 waves/SIMD.
    auto step = [&](v2f aA0, v2f aB0, v2f aA1, v2f aB1) {
        v2f bA0 = {0.f, 0.f}, bB0 = {0.f, 0.f}, bA1 = {0.f, 0.f}, bB1 = {0.f, 0.f};
        #pragma unroll
        for (int j = 0; j < 8; ++j) {
            PKFMA(aA0, whhA[j], h2a[j]);
            PKFMA(aB0, whhB[j], h2a[j]);
            PKFMA(aA1, whhA[j], h2b[j]);
            PKFMA(aB1, whhB[j], h2b[j]);
            PKFMA(bA0, whhA[j + 8], h2a[j + 8]);
            PKFMA(bB0, whhB[j + 8], h2a[j + 8]);
            PKFMA(bA1, whhA[j + 8], h2b[j + 8]);
            PKFMA(bB1, whhB[j + 8], h2b[j + 8]);
        }
        finish(aA0 + bA0, aB0 + bB0, c0, hk0);
        finish(aA1 + bA1, aB1 + bB1, c1, hk1);
        // publish: one full-wave contiguous ds_write_b32 (addr = lane):
        // half0 writes elem0's unit k, half1 writes elem1's unit k.
        hrow[lane] = isH ? hk1 : hk0;
        // broadcast read-back (wave-synchronous, compiler inserts lgkmcnt)
        const v2f* hr = reinterpret_cast<const v2f*>(hrow);
        #pragma unroll
        for (int j = 0; j < 16; ++j) { h2a[j] = hr[j]; h2b[j] = hr[16 + j]; }
    };

    // velocity, half-split: half0 reduces v1, half1 reduces v2 (same butterfly
    // order as before -> bit-identical values), one shfl_xor(32) to exchange.
    auto velocity = [&]() {
        float p0 = wsel * hk0, p1 = wsel * hk1;
        REDUCE32(p0); REDUCE32(p1);
        const float q0 = __shfl_xor(p0, 32, 64);
        const float q1 = __shfl_xor(p1, 32, 64);
        v10 = isH ? q0 : p0;  v20 = isH ? p0 : q0;
        v11 = isH ? q1 : p1;  v21 = isH ? p1 : q1;
    };

    // ---------------- encoder (x prefetched one step ahead) ----------------
    const float4* pp = poses4 + el0;        // wave-uniform addresses
    float4 x0 = pp[0], x1 = pp[1];
    for (int t = 0; t < T_enc; ++t) {
        pp += B;
        float4 xn0 = x0, xn1 = x1;
        if (t + 1 < T_enc) { xn0 = pp[0]; xn1 = pp[1]; }
        v2f aA0 = {0.f, 0.f}, aB0 = {0.f, 0.f}, aA1 = {0.f, 0.f}, aB1 = {0.f, 0.f};
        const v2f x001 = {x0.x, x0.y}, x023 = {x0.z, x0.w};
        const v2f x101 = {x1.x, x1.y}, x123 = {x1.z, x1.w};
        PKFMA(aA0, wA0, x001); PKFMA(aA0, wA1, x023);
        PKFMA(aB0, wB0, x001); PKFMA(aB0, wB1, x023);
        PKFMA(aA1, wA0, x101); PKFMA(aA1, wA1, x123);
        PKFMA(aB1, wB0, x101); PKFMA(aB1, wB1, x123);
        step(aA0, aB0, aA1, aB1);
        x0 = xn0; x1 = xn1;
    }
    const v2f p001 = {x0.x, x0.y};          // poses[-1][:,:2] per element
    const v2f p101 = {x1.x, x1.y};

    velocity();

    // decode x-part: p01 contribution is loop-invariant -> hoist
    v2f cA0 = {0.f, 0.f}, cB0 = {0.f, 0.f}, cA1 = {0.f, 0.f}, cB1 = {0.f, 0.f};
    PKFMA(cA0, wA0, p001); PKFMA(cB0, wB0, p001);
    PKFMA(cA1, wA0, p101); PKFMA(cB1, wB0, p101);

    // ---------------- decoder ----------------
    for (int t = 0; t < T_dec; ++t) {
        const float rn0 = rsqrtf(v10 * v10 + v20 * v20);
        const float cs0 = v10 * rn0, sn0 = v20 * rn0;
        const float rn1 = rsqrtf(v11 * v11 + v21 * v21);
        const float cs1 = v11 * rn1, sn1 = v21 * rn1;
        if (lane == 0) out4[(size_t)t * B + el0] = make_float4(p001.x, p001.y, cs0, sn0);
        if (lane == 1) out4[(size_t)t * B + el1] = make_float4(p101.x, p101.y, cs1, sn1);
        v2f aA0 = cA0, aB0 = cB0, aA1 = cA1, aB1 = cB1;
        const v2f cssn0 = {cs0, sn0}, cssn1 = {cs1, sn1};
        PKFMA(aA0, wA1, cssn0); PKFMA(aB0, wB1, cssn0);
        PKFMA(aA1, wA1, cssn1); PKFMA(aB1, wB1, cssn1);
        step(aA0, aB0, aA1, aB1);
        velocity();
    }
}

extern "C" void kernel_launch(void* const* d_in, const int* in_sizes, int n_in,
                              void* d_out, int out_size, void* d_ws, size_t ws_size,
                              hipStream_t stream) {
    const float* poses   = (const float*)d_in[0];
    // d_in[1] = deltas: values unused by the reference decoder (only length matters)
    const float* W_ih    = (const float*)d_in[2];
    const float* W_hh    = (const float*)d_in[3];
    const float* W_dense = (const float*)d_in[4];
    float* out = (float*)d_out;

    const int T_enc = 64;                       // fixed by the reference setup
    const int B     = in_sizes[0] / (T_enc * 4);
    const int T_dec = out_size / (B * 4);       // n_new_poses

    dim3 grid(B / 8), block(256);               // 2 elements/wave, 4 waves/block
    hipLaunchKernelGGL(lstm_dual2, grid, block, 0, stream,
                       poses, W_ih, W_hh, W_dense, out, B, T_enc, T_dec);
}